// Round 8
// baseline (2287.187 us; speedup 1.0000x reference)
//
#include <hip/hip_runtime.h>
#include <cstdint>
#include <cstddef>

// ---------------- problem constants ----------------
#define VOCAB 32000
#define EMB   256
#define HID   1024
#define NB    16      // batch
#define SS    512     // seq
#define MTOK  (NB*SS) // 8192 tokens
#define KDIM  1024    // NM1*EMB = HID
#define NCHUNK 500    // 32000 / 64 cols per chunk
#define PSTRIDE 512   // padded chunk stride

typedef __bf16 bf16_t;
typedef bf16_t bf16x8 __attribute__((ext_vector_type(8)));
typedef float  f32x4  __attribute__((ext_vector_type(4)));
typedef float  f32x16 __attribute__((ext_vector_type(16)));
typedef int    i32x4  __attribute__((ext_vector_type(4)));
typedef int    i32x8  __attribute__((ext_vector_type(8)));

__device__ __forceinline__ unsigned short f32_to_bf16(float f) {
  union { float f; unsigned int u; } v; v.f = f;
  unsigned int u = v.u;
  unsigned int r = (u + 0x7FFFu + ((u >> 16) & 1u)) >> 16; // RNE
  return (unsigned short)r;
}

// f32 -> OCP e4m3fn, RNE, software (input assumed |x| <= 448)
__device__ __forceinline__ uint8_t f32_to_e4m3(float x) {
  union { float f; uint32_t u; } v; v.f = x;
  uint32_t s = (v.u >> 24) & 0x80u;
  int e = (int)((v.u >> 23) & 0xffu) - 127;
  uint32_t m = v.u & 0x7fffffu;
  if (e < -9) return (uint8_t)s;                  // -> 0
  if (e >= -6) {                                  // normal range
    uint32_t keep = m >> 20;
    uint32_t rest = m & 0xfffffu;
    keep += (rest > 0x80000u) || (rest == 0x80000u && (keep & 1u));
    if (keep == 8u) { keep = 0u; e += 1; }
    int code = ((e + 7) << 3) | (int)keep;
    if (code >= 0x7f) code = 0x7e;                // clamp to 448 (avoid NaN)
    return (uint8_t)(s | (uint32_t)code);
  }
  // subnormal
  uint32_t full = 0x800000u | m;
  int shift = 20 + (-6 - e);                      // 21..23
  uint32_t keep = full >> shift;
  uint32_t rest = full & ((1u << shift) - 1u);
  uint32_t half = 1u << (shift - 1);
  keep += (rest > half) || (rest == half && (keep & 1u));
  if (keep >= 8u) return (uint8_t)(s | 0x08u);
  return (uint8_t)(s | keep);
}

__device__ __forceinline__ void gload_lds16(const void* gsrc, void* ldst) {
  __builtin_amdgcn_global_load_lds(
      (__attribute__((address_space(1))) void*)gsrc,
      (__attribute__((address_space(3))) void*)ldst,
      16, 0, 0);
}

// ---------------- transpose + convert: in[R][C] f32 -> out[C][R] ----------------
__global__ void k_transpose_bf16(const float* __restrict__ in,
                                 unsigned short* __restrict__ out,
                                 int R, int C) {
  __shared__ float tile[32][33];
  int bc = blockIdx.x * 32, br = blockIdx.y * 32;
  int tx = threadIdx.x & 31, ty = threadIdx.x >> 5;
#pragma unroll
  for (int i = 0; i < 32; i += 8)
    tile[ty + i][tx] = in[(size_t)(br + ty + i) * C + (bc + tx)];
  __syncthreads();
#pragma unroll
  for (int i = 0; i < 32; i += 8)
    out[(size_t)(bc + ty + i) * R + (br + tx)] = f32_to_bf16(tile[tx][ty + i]);
}

__global__ void k_transpose_fp8(const float* __restrict__ in,
                                uint8_t* __restrict__ out,
                                int R, int C) {
  __shared__ float tile[32][33];
  int bc = blockIdx.x * 32, br = blockIdx.y * 32;
  int tx = threadIdx.x & 31, ty = threadIdx.x >> 5;
#pragma unroll
  for (int i = 0; i < 32; i += 8)
    tile[ty + i][tx] = in[(size_t)(br + ty + i) * C + (bc + tx)];
  __syncthreads();
#pragma unroll
  for (int i = 0; i < 32; i += 8)
    out[(size_t)(bc + ty + i) * R + (br + tx)] = f32_to_e4m3(tile[tx][ty + i] * 16.0f);
}

// ---------------- embedding gather ----------------
__global__ void k_gather_e(const int* __restrict__ text,
                           const float* __restrict__ embed,
                           unsigned short* __restrict__ E) {
  int t = blockIdx.x;
  int b = t >> 9, s = t & 511;
  int d = threadIdx.x; // 0..255
#pragma unroll
  for (int j = 0; j < 4; ++j) {
    int sidx = s + j - 4;
    int tok = (sidx >= 0) ? text[b * SS + sidx] : 0;
    float val = (tok != 0) ? embed[(size_t)tok * EMB + d] : 0.0f;
    E[(size_t)t * KDIM + j * EMB + d] = f32_to_bf16(val);
  }
}

// ---------------- FFN GEMM (128x128 tile, relu+bias; OUTQ=1 -> fp8 x16) ----------------
template<int OUTQ>
__global__ __launch_bounds__(256)
void k_gemm_ffn(const unsigned short* __restrict__ A,
                const unsigned short* __restrict__ Bt,
                const float* __restrict__ bias,
                void* __restrict__ Hout, int N) {
  __shared__ unsigned short As[128 * 32];
  __shared__ unsigned short Bs[128 * 32];
  const int tid  = threadIdx.x;
  const int bn   = blockIdx.x, bm = blockIdx.y;
  const int lane = tid & 63, wid = tid >> 6;
  const int wm = wid >> 1, wn = wid & 1;
  const int g = lane >> 4, c = lane & 15;

  f32x4 acc[4][4];
#pragma unroll
  for (int m = 0; m < 4; ++m)
#pragma unroll
    for (int n = 0; n < 4; ++n) { f32x4 z = {0.f, 0.f, 0.f, 0.f}; acc[m][n] = z; }

  const int arow = tid >> 2;
  const int slotb = ((tid & 3) ^ ((tid >> 3) & 3)) * 16;
  const char* gA0 = (const char*)A + ((size_t)(bm * 128 + arow) * KDIM) * 2 + slotb;
  const char* gA1 = gA0 + (size_t)64 * KDIM * 2;
  const char* gB0 = (const char*)Bt + ((size_t)(bn * 128 + arow) * KDIM) * 2 + slotb;
  const char* gB1 = gB0 + (size_t)64 * KDIM * 2;
  char* lA = (char*)As + tid * 16;
  char* lB = (char*)Bs + tid * 16;

  const int rs = (g ^ ((c >> 1) & 3)) * 8;

  for (int kt = 0; kt < KDIM / 32; ++kt) {
    const int kb = kt * 64;
    gload_lds16(gA0 + kb, lA);
    gload_lds16(gA1 + kb, lA + 4096);
    gload_lds16(gB0 + kb, lB);
    gload_lds16(gB1 + kb, lB + 4096);
    __syncthreads();

    bf16x8 af[4], bf[4];
#pragma unroll
    for (int m = 0; m < 4; ++m)
      af[m] = *(const bf16x8*)&As[(wm * 64 + m * 16 + c) * 32 + rs];
#pragma unroll
    for (int n = 0; n < 4; ++n)
      bf[n] = *(const bf16x8*)&Bs[(wn * 64 + n * 16 + c) * 32 + rs];
#pragma unroll
    for (int m = 0; m < 4; ++m)
#pragma unroll
      for (int n = 0; n < 4; ++n)
        acc[m][n] = __builtin_amdgcn_mfma_f32_16x16x32_bf16(af[m], bf[n], acc[m][n], 0, 0, 0);
    __syncthreads();
  }

#pragma unroll
  for (int n = 0; n < 4; ++n) {
    int colg = bn * 128 + wn * 64 + n * 16 + c;
    float bv = bias[colg];
#pragma unroll
    for (int m = 0; m < 4; ++m)
#pragma unroll
      for (int j = 0; j < 4; ++j) {
        int rowg = bm * 128 + wm * 64 + m * 16 + g * 4 + j;
        float v = acc[m][n][j] + bv;
        v = v > 0.f ? v : 0.f;
        if constexpr (OUTQ == 0)
          ((unsigned short*)Hout)[(size_t)rowg * N + colg] = f32_to_bf16(v);
        else
          ((uint8_t*)Hout)[(size_t)rowg * N + colg] = f32_to_e4m3(v * 16.0f);
      }
  }
}

// ---------------- vocab GEMM: MX-fp8, 128x256 block, BK=64, 4 waves, dbuf ------
// A/B pre-scaled by 2^4; MFMA scale operands 2^-4 (e8m0 byte 123).
// R8 geometry: per-wave 64x128 (acc[2][4] = 128 regs) -> 1.5 LDS reads/MFMA
// (was 2.0). ~200 unified regs at __launch_bounds__(256,2): 2 waves/SIMD,
// 2 independent blocks/CU (LDS 48KB) for cross-block stall hiding.
// K-loop fully unrolled: staging/read addresses fold to SGPR-base + imm.
__global__ __launch_bounds__(256, 2)
void k_gemm_vocab_mx(const uint8_t* __restrict__ Aq,   // [MTOK][KDIM] fp8 (x16)
                     const uint8_t* __restrict__ Bq,   // [VOCAB][KDIM] fp8 (x16)
                     const float* __restrict__ bias,
                     float* __restrict__ pmax, float* __restrict__ psum,
                     float* __restrict__ tlog, const int* __restrict__ target) {
  __shared__ uint8_t As[2][128 * 64];  // 16 KB
  __shared__ uint8_t Bs[2][256 * 64];  // 32 KB
  const int tid  = threadIdx.x;
  const int lane = tid & 63, wid = tid >> 6;   // 4 waves
  const int wm = wid >> 1, wn = wid & 1;       // 2(M) x 2(N); per-wave out 64x128
  const int lr = lane & 31, kb = lane >> 5;
  const int kb2 = kb << 1;

  // bijective XCD-chunked swizzle; grid = 8000 = 64(bm) x 125(bn)
  const int o   = blockIdx.x;
  const int xcd = o & 7, idx = o >> 3;         // idx 0..999
  const int bm  = xcd * 8 + (idx & 7);         // 0..63
  const int bn  = idx >> 3;                    // 0..124

  f32x16 acc[2][4];
#pragma unroll
  for (int m = 0; m < 2; ++m)
#pragma unroll
    for (int n = 0; n < 4; ++n)
#pragma unroll
      for (int e = 0; e < 16; ++e) acc[m][n][e] = 0.f;

  // staging: thread t -> row (t>>2)+64h, LDS quad t&3; source quad (t&3)^((row>>1)&3)
  // ((row>>1)&3 invariant under row += 64)
  const int srow = tid >> 2, sq = tid & 3;
  const int gq = sq ^ ((srow >> 1) & 3);
  const uint8_t* pA = Aq + (size_t)bm * 128 * KDIM + (size_t)srow * KDIM + gq * 16;
  const uint8_t* pB = Bq + (size_t)bn * 256 * KDIM + (size_t)srow * KDIM + gq * 16;
  uint8_t* lA0 = &As[0][0] + tid * 16;
  uint8_t* lB0 = &Bs[0][0] + tid * 16;
  uint8_t* lA1 = &As[1][0] + tid * 16;
  uint8_t* lB1 = &Bs[1][0] + tid * 16;

  // A: 128 rows = 2 issues (64*KDIM = 65536 B apart); B: 256 rows = 4 issues.
#define STAGE(kt, d) do {                                                  \
    const size_t ko_ = (size_t)(kt) * 64;                                  \
    uint8_t* la_ = (d) ? lA1 : lA0;                                        \
    uint8_t* lb_ = (d) ? lB1 : lB0;                                        \
    gload_lds16(pA + ko_,          la_);                                   \
    gload_lds16(pA + ko_ + 65536,  la_ + 4096);                            \
    gload_lds16(pB + ko_,          lb_);                                   \
    gload_lds16(pB + ko_ + 65536,  lb_ + 4096);                            \
    gload_lds16(pB + ko_ + 131072, lb_ + 8192);                            \
    gload_lds16(pB + ko_ + 196608, lb_ + 12288);                           \
  } while (0)

  const int swz = (lr >> 1) & 3;

  STAGE(0, 0);
  __syncthreads();  // tile 0 resident

#pragma unroll
  for (int kt = 0; kt < 16; ++kt) {
    const int buf = kt & 1;
    if (kt + 1 < 16) STAGE(kt + 1, buf ^ 1);   // issue next-tile loads early

    i32x8 b[4];
#pragma unroll
    for (int n = 0; n < 4; ++n) {
      const uint8_t* pb = &Bs[buf][0] + (wn * 128 + n * 32 + lr) * 64;
      i32x4 lo = *(const i32x4*)(pb + ((kb2 | 0) ^ swz) * 16);
      i32x4 hi = *(const i32x4*)(pb + ((kb2 | 1) ^ swz) * 16);
      b[n] = __builtin_shufflevector(lo, hi, 0, 1, 2, 3, 4, 5, 6, 7);
    }
    __builtin_amdgcn_s_setprio(1);
#pragma unroll
    for (int m = 0; m < 2; ++m) {
      const uint8_t* pa = &As[buf][0] + (wm * 64 + m * 32 + lr) * 64;
      i32x4 lo = *(const i32x4*)(pa + ((kb2 | 0) ^ swz) * 16);
      i32x4 hi = *(const i32x4*)(pa + ((kb2 | 1) ^ swz) * 16);
      i32x8 am = __builtin_shufflevector(lo, hi, 0, 1, 2, 3, 4, 5, 6, 7);
#pragma unroll
      for (int n = 0; n < 4; ++n)
        acc[m][n] = __builtin_amdgcn_mfma_scale_f32_32x32x64_f8f6f4(
            am, b[n], acc[m][n], 0, 0, 0, 123, 0, 123);
    }
    __builtin_amdgcn_s_setprio(0);
    __syncthreads();  // reads done + prefetch landed (vmcnt drained)
  }
#undef STAGE

  // ---- epilogue: fused softmax stats per 64-col chunk (2 chunks/wave) ----
  // C/D 32x32 layout: col = lane&31, row = (reg&3) + 8*(reg>>2) + 4*(lane>>5)
  const int colbase = bn * 256 + wn * 128;
  const int chunk0 = bn * 4 + wn * 2;
  float bov[4];
#pragma unroll
  for (int n = 0; n < 4; ++n) bov[n] = bias[colbase + n * 32 + lr];
#pragma unroll
  for (int m = 0; m < 2; ++m) {
#pragma unroll
    for (int reg = 0; reg < 16; ++reg) {
      int rowg = bm * 128 + wm * 64 + m * 32 + (reg & 3) + 8 * (reg >> 2) + 4 * kb;
      float v0 = acc[m][0][reg] + bov[0];
      float v1 = acc[m][1][reg] + bov[1];
      float v2 = acc[m][2][reg] + bov[2];
      float v3 = acc[m][3][reg] + bov[3];
#pragma unroll
      for (int h = 0; h < 2; ++h) {
        float x0 = (h == 0) ? v0 : v2;
        float x1 = (h == 0) ? v1 : v3;
        float mv = fmaxf(x0, x1);
#pragma unroll
        for (int sft = 1; sft < 32; sft <<= 1) mv = fmaxf(mv, __shfl_xor(mv, sft));
        float se = __expf(x0 - mv) + __expf(x1 - mv);
#pragma unroll
        for (int sft = 1; sft < 32; sft <<= 1) se += __shfl_xor(se, sft);
        if (lr == 0) {
          pmax[(size_t)rowg * PSTRIDE + chunk0 + h] = mv;
          psum[(size_t)rowg * PSTRIDE + chunk0 + h] = se;
        }
      }
      int cwz = target[rowg] - colbase;
      if (cwz >= 0 && cwz < 128 && lr == (cwz & 31)) {
        int nn = cwz >> 5;
        float tv = (nn == 0) ? v0 : (nn == 1) ? v1 : (nn == 2) ? v2 : v3;
        tlog[rowg] = tv;
      }
    }
  }
}

// ---------------- combine per-chunk stats -> nll per row ----------------
__global__ void k_reduce_nll(const float* __restrict__ pmax,
                             const float* __restrict__ psum,
                             const float* __restrict__ tlog,
                             float* __restrict__ nll) {
  int row = blockIdx.x;
  int lane = threadIdx.x; // 64
  float M = -1e30f;
  for (int ch = lane; ch < NCHUNK; ch += 64) M = fmaxf(M, pmax[(size_t)row * PSTRIDE + ch]);
#pragma unroll
  for (int s = 1; s < 64; s <<= 1) M = fmaxf(M, __shfl_xor(M, s));
  float L = 0.f;
  for (int ch = lane; ch < NCHUNK; ch += 64)
    L += __expf(pmax[(size_t)row * PSTRIDE + ch] - M) * psum[(size_t)row * PSTRIDE + ch];
#pragma unroll
  for (int s = 1; s < 64; s <<= 1) L += __shfl_xor(L, s);
  if (lane == 0) nll[row] = -(tlog[row] - M - logf(L));
}

// ---------------- masked per-step mean -> scalar loss ----------------
__global__ void k_loss(const int* __restrict__ target,
                       const float* __restrict__ nll,
                       float* __restrict__ out) {
  __shared__ float red[SS];
  int s = threadIdx.x; // 512
  float sl = 0.f, cnt = 0.f;
#pragma unroll
  for (int b = 0; b < NB; ++b) {
    int idx = b * SS + s;
    if (target[idx] != 0) { sl += nll[idx]; cnt += 1.f; }
  }
  red[s] = sl / fmaxf(cnt, 1.f);
  __syncthreads();
  for (int st = 256; st > 0; st >>= 1) {
    if (s < st) red[s] += red[s + st];
    __syncthreads();
  }
  if (s == 0) out[0] = red[0] / (float)SS;
}

// ---------------- launch ----------------
extern "C" void kernel_launch(void* const* d_in, const int* in_sizes, int n_in,
                              void* d_out, int out_size, void* d_ws, size_t ws_size,
                              hipStream_t stream) {
  (void)in_sizes; (void)n_in; (void)out_size; (void)ws_size;
  const int*   text   = (const int*)d_in[0];
  const int*   target = (const int*)d_in[1];
  const float* embed  = (const float*)d_in[2];
  const float* W1     = (const float*)d_in[3];
  const float* b1     = (const float*)d_in[4];
  const float* W2     = (const float*)d_in[5];
  const float* b2     = (const float*)d_in[6];
  const float* Wo     = (const float*)d_in[7];
  const float* bo     = (const float*)d_in[8];
  float* out = (float*)d_out;
  char* ws = (char*)d_ws;

  const size_t SZ_E = (size_t)MTOK * KDIM * 2;          // 16.78 MB (bf16)
  unsigned short* E   = (unsigned short*)(ws);
  unsigned short* H1  = (unsigned short*)(ws + SZ_E);
  uint8_t*        H2Q = (uint8_t*)(ws + 2 * SZ_E);      // fp8, 8.39 MB
  char* p = ws + 2 * SZ_E + (size_t)MTOK * KDIM;
  unsigned short* W1t = (unsigned short*)p;  p += (size_t)HID * HID * 2;
  unsigned short* W2t = (unsigned short*)p;  p += (size_t)HID * HID * 2;
  uint8_t*        WoQ = (uint8_t*)p;         p += (size_t)VOCAB * HID;   // fp8, 32.77 MB
  float* tlog = (float*)p;                   p += (size_t)MTOK * 4;
  float* nll  = (float*)p;
  float* pmax = (float*)E;   // E dead after GEMM1
  float* psum = (float*)H1;  // H1 dead after GEMM2

  k_transpose_bf16<<<dim3(HID / 32, HID / 32), 256, 0, stream>>>(W1, W1t, HID, HID);
  k_transpose_bf16<<<dim3(HID / 32, HID / 32), 256, 0, stream>>>(W2, W2t, HID, HID);
  k_transpose_fp8 <<<dim3(VOCAB / 32, HID / 32), 256, 0, stream>>>(Wo, WoQ, HID, VOCAB);
  k_gather_e<<<MTOK, 256, 0, stream>>>(text, embed, E);

  k_gemm_ffn<0><<<dim3(HID / 128, MTOK / 128), 256, 0, stream>>>(E, W1t, b1, (void*)H1, HID);
  k_gemm_ffn<1><<<dim3(HID / 128, MTOK / 128), 256, 0, stream>>>(H1, W2t, b2, (void*)H2Q, HID);

  k_gemm_vocab_mx<<<dim3((MTOK / 128) * (VOCAB / 256)), 256, 0, stream>>>(
      H2Q, WoQ, bo, pmax, psum, tlog, target);

  k_reduce_nll<<<MTOK, 64, 0, stream>>>(pmax, psum, tlog, nll);
  k_loss<<<1, SS, 0, stream>>>(target, nll, out);
}

// Round 9
// 1577.311 us; speedup vs baseline: 1.4501x; 1.4501x over previous
//
#include <hip/hip_runtime.h>
#include <cstdint>
#include <cstddef>

// ---------------- problem constants ----------------
#define VOCAB 32000
#define EMB   256
#define HID   1024
#define NB    16      // batch
#define SS    512     // seq
#define MTOK  (NB*SS) // 8192 tokens
#define KDIM  1024    // NM1*EMB = HID
#define NCHUNK 500    // 32000 / 64 cols per chunk
#define PSTRIDE 512   // padded chunk stride

typedef __bf16 bf16_t;
typedef bf16_t bf16x8 __attribute__((ext_vector_type(8)));
typedef float  f32x4  __attribute__((ext_vector_type(4)));
typedef float  f32x16 __attribute__((ext_vector_type(16)));
typedef int    i32x4  __attribute__((ext_vector_type(4)));
typedef int    i32x8  __attribute__((ext_vector_type(8)));

__device__ __forceinline__ unsigned short f32_to_bf16(float f) {
  union { float f; unsigned int u; } v; v.f = f;
  unsigned int u = v.u;
  unsigned int r = (u + 0x7FFFu + ((u >> 16) & 1u)) >> 16; // RNE
  return (unsigned short)r;
}

// f32 -> OCP e4m3fn, RNE, software (input assumed |x| <= 448)
__device__ __forceinline__ uint8_t f32_to_e4m3(float x) {
  union { float f; uint32_t u; } v; v.f = x;
  uint32_t s = (v.u >> 24) & 0x80u;
  int e = (int)((v.u >> 23) & 0xffu) - 127;
  uint32_t m = v.u & 0x7fffffu;
  if (e < -9) return (uint8_t)s;                  // -> 0
  if (e >= -6) {                                  // normal range
    uint32_t keep = m >> 20;
    uint32_t rest = m & 0xfffffu;
    keep += (rest > 0x80000u) || (rest == 0x80000u && (keep & 1u));
    if (keep == 8u) { keep = 0u; e += 1; }
    int code = ((e + 7) << 3) | (int)keep;
    if (code >= 0x7f) code = 0x7e;                // clamp to 448 (avoid NaN)
    return (uint8_t)(s | (uint32_t)code);
  }
  // subnormal
  uint32_t full = 0x800000u | m;
  int shift = 20 + (-6 - e);                      // 21..23
  uint32_t keep = full >> shift;
  uint32_t rest = full & ((1u << shift) - 1u);
  uint32_t half = 1u << (shift - 1);
  keep += (rest > half) || (rest == half && (keep & 1u));
  if (keep >= 8u) return (uint8_t)(s | 0x08u);
  return (uint8_t)(s | keep);
}

__device__ __forceinline__ void gload_lds16(const void* gsrc, void* ldst) {
  __builtin_amdgcn_global_load_lds(
      (__attribute__((address_space(1))) void*)gsrc,
      (__attribute__((address_space(3))) void*)ldst,
      16, 0, 0);
}

// ---------------- transpose + convert: in[R][C] f32 -> out[C][R] ----------------
__global__ void k_transpose_bf16(const float* __restrict__ in,
                                 unsigned short* __restrict__ out,
                                 int R, int C) {
  __shared__ float tile[32][33];
  int bc = blockIdx.x * 32, br = blockIdx.y * 32;
  int tx = threadIdx.x & 31, ty = threadIdx.x >> 5;
#pragma unroll
  for (int i = 0; i < 32; i += 8)
    tile[ty + i][tx] = in[(size_t)(br + ty + i) * C + (bc + tx)];
  __syncthreads();
#pragma unroll
  for (int i = 0; i < 32; i += 8)
    out[(size_t)(bc + ty + i) * R + (br + tx)] = f32_to_bf16(tile[tx][ty + i]);
}

__global__ void k_transpose_fp8(const float* __restrict__ in,
                                uint8_t* __restrict__ out,
                                int R, int C) {
  __shared__ float tile[32][33];
  int bc = blockIdx.x * 32, br = blockIdx.y * 32;
  int tx = threadIdx.x & 31, ty = threadIdx.x >> 5;
#pragma unroll
  for (int i = 0; i < 32; i += 8)
    tile[ty + i][tx] = in[(size_t)(br + ty + i) * C + (bc + tx)];
  __syncthreads();
#pragma unroll
  for (int i = 0; i < 32; i += 8)
    out[(size_t)(bc + ty + i) * R + (br + tx)] = f32_to_e4m3(tile[tx][ty + i] * 16.0f);
}

// ---------------- embedding gather ----------------
__global__ void k_gather_e(const int* __restrict__ text,
                           const float* __restrict__ embed,
                           unsigned short* __restrict__ E) {
  int t = blockIdx.x;
  int b = t >> 9, s = t & 511;
  int d = threadIdx.x; // 0..255
#pragma unroll
  for (int j = 0; j < 4; ++j) {
    int sidx = s + j - 4;
    int tok = (sidx >= 0) ? text[b * SS + sidx] : 0;
    float val = (tok != 0) ? embed[(size_t)tok * EMB + d] : 0.0f;
    E[(size_t)t * KDIM + j * EMB + d] = f32_to_bf16(val);
  }
}

// ---------------- FFN GEMM (128x128 tile, relu+bias; OUTQ=1 -> fp8 x16) ----------------
template<int OUTQ>
__global__ __launch_bounds__(256)
void k_gemm_ffn(const unsigned short* __restrict__ A,
                const unsigned short* __restrict__ Bt,
                const float* __restrict__ bias,
                void* __restrict__ Hout, int N) {
  __shared__ unsigned short As[128 * 32];
  __shared__ unsigned short Bs[128 * 32];
  const int tid  = threadIdx.x;
  const int bn   = blockIdx.x, bm = blockIdx.y;
  const int lane = tid & 63, wid = tid >> 6;
  const int wm = wid >> 1, wn = wid & 1;
  const int g = lane >> 4, c = lane & 15;

  f32x4 acc[4][4];
#pragma unroll
  for (int m = 0; m < 4; ++m)
#pragma unroll
    for (int n = 0; n < 4; ++n) { f32x4 z = {0.f, 0.f, 0.f, 0.f}; acc[m][n] = z; }

  const int arow = tid >> 2;
  const int slotb = ((tid & 3) ^ ((tid >> 3) & 3)) * 16;
  const char* gA0 = (const char*)A + ((size_t)(bm * 128 + arow) * KDIM) * 2 + slotb;
  const char* gA1 = gA0 + (size_t)64 * KDIM * 2;
  const char* gB0 = (const char*)Bt + ((size_t)(bn * 128 + arow) * KDIM) * 2 + slotb;
  const char* gB1 = gB0 + (size_t)64 * KDIM * 2;
  char* lA = (char*)As + tid * 16;
  char* lB = (char*)Bs + tid * 16;

  const int rs = (g ^ ((c >> 1) & 3)) * 8;

  for (int kt = 0; kt < KDIM / 32; ++kt) {
    const int kb = kt * 64;
    gload_lds16(gA0 + kb, lA);
    gload_lds16(gA1 + kb, lA + 4096);
    gload_lds16(gB0 + kb, lB);
    gload_lds16(gB1 + kb, lB + 4096);
    __syncthreads();

    bf16x8 af[4], bf[4];
#pragma unroll
    for (int m = 0; m < 4; ++m)
      af[m] = *(const bf16x8*)&As[(wm * 64 + m * 16 + c) * 32 + rs];
#pragma unroll
    for (int n = 0; n < 4; ++n)
      bf[n] = *(const bf16x8*)&Bs[(wn * 64 + n * 16 + c) * 32 + rs];
#pragma unroll
    for (int m = 0; m < 4; ++m)
#pragma unroll
      for (int n = 0; n < 4; ++n)
        acc[m][n] = __builtin_amdgcn_mfma_f32_16x16x32_bf16(af[m], bf[n], acc[m][n], 0, 0, 0);
    __syncthreads();
  }

#pragma unroll
  for (int n = 0; n < 4; ++n) {
    int colg = bn * 128 + wn * 64 + n * 16 + c;
    float bv = bias[colg];
#pragma unroll
    for (int m = 0; m < 4; ++m)
#pragma unroll
      for (int j = 0; j < 4; ++j) {
        int rowg = bm * 128 + wm * 64 + m * 16 + g * 4 + j;
        float v = acc[m][n][j] + bv;
        v = v > 0.f ? v : 0.f;
        if constexpr (OUTQ == 0)
          ((unsigned short*)Hout)[(size_t)rowg * N + colg] = f32_to_bf16(v);
        else
          ((uint8_t*)Hout)[(size_t)rowg * N + colg] = f32_to_e4m3(v * 16.0f);
      }
  }
}

// ---------------- vocab GEMM: MX-fp8, 128x128 block, BK=64, 4 waves (R7 geometry) -----
// A/B pre-scaled by 2^4; MFMA scale operands 2^-4 (e8m0 byte 123).
// R9 = R7 (proven 572us, no spill: 64 arch + 64 acc = 128 unified) + lean scheduling:
//  - full 16-iter unroll, compile-time buf -> LDS read addrs loop-invariant
//    (buf toggle folds into ds_read 16-bit imm), staging addr = fixed ptr + imm.
//  - hoisted row-base pointers and swizzle quad offsets.
//  - setprio(1) around the MFMA cluster (2 blocks/CU -> phase diversity).
__global__ __launch_bounds__(256, 2)
void k_gemm_vocab_mx(const uint8_t* __restrict__ Aq,   // [MTOK][KDIM] fp8 (x16)
                     const uint8_t* __restrict__ Bq,   // [VOCAB][KDIM] fp8 (x16)
                     const float* __restrict__ bias,
                     float* __restrict__ pmax, float* __restrict__ psum,
                     float* __restrict__ tlog, const int* __restrict__ target) {
  __shared__ uint8_t As[2][128 * 64];  // 16 KB
  __shared__ uint8_t Bs[2][128 * 64];  // 16 KB
  const int tid  = threadIdx.x;
  const int lane = tid & 63, wid = tid >> 6;   // 4 waves
  const int wm = wid >> 1, wn = wid & 1;       // 2(M) x 2(N); per-wave out 64x64
  const int lr = lane & 31, kb = lane >> 5;
  const int kb2 = kb << 1;

  // bijective XCD-chunked swizzle; grid = 16000 = 64(bm) x 250(bn)
  const int o   = blockIdx.x;
  const int xcd = o & 7, idx = o >> 3;         // idx 0..1999
  const int bm  = xcd * 8 + (idx & 7);         // 0..63
  const int bn  = idx >> 3;                    // 0..249

  f32x16 acc[2][2];
#pragma unroll
  for (int m = 0; m < 2; ++m)
#pragma unroll
    for (int n = 0; n < 2; ++n)
#pragma unroll
      for (int e = 0; e < 16; ++e) acc[m][n][e] = 0.f;

  // staging: thread t -> row (t>>2)+64h, LDS quad t&3; source quad (t&3)^((row>>1)&3)
  // ((row>>1)&3 invariant under row += 64)
  const int srow = tid >> 2, sq = tid & 3;
  const int gq = sq ^ ((srow >> 1) & 3);
  const uint8_t* pA = Aq + (size_t)bm * 128 * KDIM + (size_t)srow * KDIM + gq * 16;
  const uint8_t* pB = Bq + (size_t)bn * 128 * KDIM + (size_t)srow * KDIM + gq * 16;
  uint8_t* const lA = &As[0][0] + tid * 16;
  uint8_t* const lB = &Bs[0][0] + tid * 16;

  // d_ is compile-time in the unrolled loop: dest offset folds to imm (+8192 for buf1)
#define STAGE(kt_, d_) do {                                                \
    const size_t ko_ = (size_t)(kt_) * 64;                                 \
    gload_lds16(pA + ko_,         lA + (d_) * 8192);                       \
    gload_lds16(pA + ko_ + 65536, lA + (d_) * 8192 + 4096);                \
    gload_lds16(pB + ko_,         lB + (d_) * 8192);                       \
    gload_lds16(pB + ko_ + 65536, lB + (d_) * 8192 + 4096);                \
  } while (0)

  // hoisted read addressing: row bases (buf0) + swizzled quad byte offsets
  const int swz = (lr >> 1) & 3;
  const int q0 = ((kb2 | 0) ^ swz) * 16;
  const int q1 = ((kb2 | 1) ^ swz) * 16;
  const uint8_t* const aR0 = &As[0][(wm * 64 +      lr) * 64];
  const uint8_t* const aR1 = &As[0][(wm * 64 + 32 + lr) * 64];
  const uint8_t* const bR0 = &Bs[0][(wn * 64 +      lr) * 64];
  const uint8_t* const bR1 = &Bs[0][(wn * 64 + 32 + lr) * 64];

#define RD(dst_, base_, bofs_) do {                                        \
    i32x4 lo_ = *(const i32x4*)((base_) + (bofs_) + q0);                   \
    i32x4 hi_ = *(const i32x4*)((base_) + (bofs_) + q1);                   \
    dst_ = __builtin_shufflevector(lo_, hi_, 0, 1, 2, 3, 4, 5, 6, 7);      \
  } while (0)

  STAGE(0, 0);
  __syncthreads();  // tile 0 resident

#pragma unroll
  for (int kt = 0; kt < 16; ++kt) {
    const int buf = kt & 1;              // compile-time after unroll
    if (kt + 1 < 16) STAGE(kt + 1, buf ^ 1);

    i32x8 b0, b1, a0, a1;
    RD(b0, bR0, buf * 8192);
    RD(b1, bR1, buf * 8192);
    RD(a0, aR0, buf * 8192);
    RD(a1, aR1, buf * 8192);

    __builtin_amdgcn_s_setprio(1);
    acc[0][0] = __builtin_amdgcn_mfma_scale_f32_32x32x64_f8f6f4(a0, b0, acc[0][0], 0, 0, 0, 123, 0, 123);
    acc[0][1] = __builtin_amdgcn_mfma_scale_f32_32x32x64_f8f6f4(a0, b1, acc[0][1], 0, 0, 0, 123, 0, 123);
    acc[1][0] = __builtin_amdgcn_mfma_scale_f32_32x32x64_f8f6f4(a1, b0, acc[1][0], 0, 0, 0, 123, 0, 123);
    acc[1][1] = __builtin_amdgcn_mfma_scale_f32_32x32x64_f8f6f4(a1, b1, acc[1][1], 0, 0, 0, 123, 0, 123);
    __builtin_amdgcn_s_setprio(0);

    __syncthreads();  // reads done + prefetch landed (vmcnt drained)
  }
#undef STAGE
#undef RD

  // ---- epilogue: fused softmax stats per 64-col wave chunk ----
  // C/D 32x32 layout: col = lane&31, row = (reg&3) + 8*(reg>>2) + 4*(lane>>5)
  const int chunk = bn * 2 + wn;
  const int colbase = bn * 128 + wn * 64;
  float bov0 = bias[colbase + lr];
  float bov1 = bias[colbase + 32 + lr];
#pragma unroll
  for (int m = 0; m < 2; ++m) {
#pragma unroll
    for (int reg = 0; reg < 16; ++reg) {
      int rowg = bm * 128 + wm * 64 + m * 32 + (reg & 3) + 8 * (reg >> 2) + 4 * kb;
      float v0 = acc[m][0][reg] + bov0;
      float v1 = acc[m][1][reg] + bov1;
      float mv = fmaxf(v0, v1);
#pragma unroll
      for (int sft = 1; sft < 32; sft <<= 1) mv = fmaxf(mv, __shfl_xor(mv, sft));
      float se = __expf(v0 - mv) + __expf(v1 - mv);
#pragma unroll
      for (int sft = 1; sft < 32; sft <<= 1) se += __shfl_xor(se, sft);
      if (lr == 0) {
        pmax[(size_t)rowg * PSTRIDE + chunk] = mv;
        psum[(size_t)rowg * PSTRIDE + chunk] = se;
      }
      int cw = target[rowg] - colbase;
      if (cw >= 0 && cw < 64 && lr == (cw & 31)) {
        tlog[rowg] = (cw < 32) ? v0 : v1;
      }
    }
  }
}

// ---------------- combine per-chunk stats -> nll per row ----------------
__global__ void k_reduce_nll(const float* __restrict__ pmax,
                             const float* __restrict__ psum,
                             const float* __restrict__ tlog,
                             float* __restrict__ nll) {
  int row = blockIdx.x;
  int lane = threadIdx.x; // 64
  float M = -1e30f;
  for (int ch = lane; ch < NCHUNK; ch += 64) M = fmaxf(M, pmax[(size_t)row * PSTRIDE + ch]);
#pragma unroll
  for (int s = 1; s < 64; s <<= 1) M = fmaxf(M, __shfl_xor(M, s));
  float L = 0.f;
  for (int ch = lane; ch < NCHUNK; ch += 64)
    L += __expf(pmax[(size_t)row * PSTRIDE + ch] - M) * psum[(size_t)row * PSTRIDE + ch];
#pragma unroll
  for (int s = 1; s < 64; s <<= 1) L += __shfl_xor(L, s);
  if (lane == 0) nll[row] = -(tlog[row] - M - logf(L));
}

// ---------------- masked per-step mean -> scalar loss ----------------
__global__ void k_loss(const int* __restrict__ target,
                       const float* __restrict__ nll,
                       float* __restrict__ out) {
  __shared__ float red[SS];
  int s = threadIdx.x; // 512
  float sl = 0.f, cnt = 0.f;
#pragma unroll
  for (int b = 0; b < NB; ++b) {
    int idx = b * SS + s;
    if (target[idx] != 0) { sl += nll[idx]; cnt += 1.f; }
  }
  red[s] = sl / fmaxf(cnt, 1.f);
  __syncthreads();
  for (int st = 256; st > 0; st >>= 1) {
    if (s < st) red[s] += red[s + st];
    __syncthreads();
  }
  if (s == 0) out[0] = red[0] / (float)SS;
}

// ---------------- launch ----------------
extern "C" void kernel_launch(void* const* d_in, const int* in_sizes, int n_in,
                              void* d_out, int out_size, void* d_ws, size_t ws_size,
                              hipStream_t stream) {
  (void)in_sizes; (void)n_in; (void)out_size; (void)ws_size;
  const int*   text   = (const int*)d_in[0];
  const int*   target = (const int*)d_in[1];
  const float* embed  = (const float*)d_in[2];
  const float* W1     = (const float*)d_in[3];
  const float* b1     = (const float*)d_in[4];
  const float* W2     = (const float*)d_in[5];
  const float* b2     = (const float*)d_in[6];
  const float* Wo     = (const float*)d_in[7];
  const float* bo     = (const float*)d_in[8];
  float* out = (float*)d_out;
  char* ws = (char*)d_ws;

  const size_t SZ_E = (size_t)MTOK * KDIM * 2;          // 16.78 MB (bf16)
  unsigned short* E   = (unsigned short*)(ws);
  unsigned short* H1  = (unsigned short*)(ws + SZ_E);
  uint8_t*        H2Q = (uint8_t*)(ws + 2 * SZ_E);      // fp8, 8.39 MB
  char* p = ws + 2 * SZ_E + (size_t)MTOK * KDIM;
  unsigned short* W1t = (unsigned short*)p;  p += (size_t)HID * HID * 2;
  unsigned short* W2t = (unsigned short*)p;  p += (size_t)HID * HID * 2;
  uint8_t*        WoQ = (uint8_t*)p;         p += (size_t)VOCAB * HID;   // fp8, 32.77 MB
  float* tlog = (float*)p;                   p += (size_t)MTOK * 4;
  float* nll  = (float*)p;
  float* pmax = (float*)E;   // E dead after GEMM1
  float* psum = (float*)H1;  // H1 dead after GEMM2

  k_transpose_bf16<<<dim3(HID / 32, HID / 32), 256, 0, stream>>>(W1, W1t, HID, HID);
  k_transpose_bf16<<<dim3(HID / 32, HID / 32), 256, 0, stream>>>(W2, W2t, HID, HID);
  k_transpose_fp8 <<<dim3(VOCAB / 32, HID / 32), 256, 0, stream>>>(Wo, WoQ, HID, VOCAB);
  k_gather_e<<<MTOK, 256, 0, stream>>>(text, embed, E);

  k_gemm_ffn<0><<<dim3(HID / 128, MTOK / 128), 256, 0, stream>>>(E, W1t, b1, (void*)H1, HID);
  k_gemm_ffn<1><<<dim3(HID / 128, MTOK / 128), 256, 0, stream>>>(H1, W2t, b2, (void*)H2Q, HID);

  k_gemm_vocab_mx<<<dim3((MTOK / 128) * (VOCAB / 128)), 256, 0, stream>>>(
      H2Q, WoQ, bo, pmax, psum, tlog, target);

  k_reduce_nll<<<MTOK, 64, 0, stream>>>(pmax, psum, tlog, nll);
  k_loss<<<1, SS, 0, stream>>>(target, nll, out);
}

// Round 10
// 784.440 us; speedup vs baseline: 2.9157x; 2.0107x over previous
//
#include <hip/hip_runtime.h>
#include <cstdint>
#include <cstddef>

// ---------------- problem constants ----------------
#define VOCAB 32000
#define EMB   256
#define HID   1024
#define NB    16      // batch
#define SS    512     // seq
#define MTOK  (NB*SS) // 8192 tokens
#define KDIM  1024    // NM1*EMB = HID
#define NCHUNK 500    // 32000 / 64 cols per chunk
#define PSTRIDE 512   // padded chunk stride

typedef __bf16 bf16_t;
typedef bf16_t bf16x8 __attribute__((ext_vector_type(8)));
typedef float  f32x4  __attribute__((ext_vector_type(4)));
typedef float  f32x16 __attribute__((ext_vector_type(16)));
typedef int    i32x4  __attribute__((ext_vector_type(4)));
typedef int    i32x8  __attribute__((ext_vector_type(8)));

__device__ __forceinline__ unsigned short f32_to_bf16(float f) {
  union { float f; unsigned int u; } v; v.f = f;
  unsigned int u = v.u;
  unsigned int r = (u + 0x7FFFu + ((u >> 16) & 1u)) >> 16; // RNE
  return (unsigned short)r;
}

// f32 -> OCP e4m3fn, RNE, software (input assumed |x| <= 448)
__device__ __forceinline__ uint8_t f32_to_e4m3(float x) {
  union { float f; uint32_t u; } v; v.f = x;
  uint32_t s = (v.u >> 24) & 0x80u;
  int e = (int)((v.u >> 23) & 0xffu) - 127;
  uint32_t m = v.u & 0x7fffffu;
  if (e < -9) return (uint8_t)s;                  // -> 0
  if (e >= -6) {                                  // normal range
    uint32_t keep = m >> 20;
    uint32_t rest = m & 0xfffffu;
    keep += (rest > 0x80000u) || (rest == 0x80000u && (keep & 1u));
    if (keep == 8u) { keep = 0u; e += 1; }
    int code = ((e + 7) << 3) | (int)keep;
    if (code >= 0x7f) code = 0x7e;                // clamp to 448 (avoid NaN)
    return (uint8_t)(s | (uint32_t)code);
  }
  // subnormal
  uint32_t full = 0x800000u | m;
  int shift = 20 + (-6 - e);                      // 21..23
  uint32_t keep = full >> shift;
  uint32_t rest = full & ((1u << shift) - 1u);
  uint32_t half = 1u << (shift - 1);
  keep += (rest > half) || (rest == half && (keep & 1u));
  if (keep >= 8u) return (uint8_t)(s | 0x08u);
  return (uint8_t)(s | keep);
}

__device__ __forceinline__ void gload_lds16(const void* gsrc, void* ldst) {
  __builtin_amdgcn_global_load_lds(
      (__attribute__((address_space(1))) void*)gsrc,
      (__attribute__((address_space(3))) void*)ldst,
      16, 0, 0);
}

// ---------------- transpose + convert: in[R][C] f32 -> out[C][R] ----------------
__global__ void k_transpose_bf16(const float* __restrict__ in,
                                 unsigned short* __restrict__ out,
                                 int R, int C) {
  __shared__ float tile[32][33];
  int bc = blockIdx.x * 32, br = blockIdx.y * 32;
  int tx = threadIdx.x & 31, ty = threadIdx.x >> 5;
#pragma unroll
  for (int i = 0; i < 32; i += 8)
    tile[ty + i][tx] = in[(size_t)(br + ty + i) * C + (bc + tx)];
  __syncthreads();
#pragma unroll
  for (int i = 0; i < 32; i += 8)
    out[(size_t)(bc + ty + i) * R + (br + tx)] = f32_to_bf16(tile[tx][ty + i]);
}

__global__ void k_transpose_fp8(const float* __restrict__ in,
                                uint8_t* __restrict__ out,
                                int R, int C) {
  __shared__ float tile[32][33];
  int bc = blockIdx.x * 32, br = blockIdx.y * 32;
  int tx = threadIdx.x & 31, ty = threadIdx.x >> 5;
#pragma unroll
  for (int i = 0; i < 32; i += 8)
    tile[ty + i][tx] = in[(size_t)(br + ty + i) * C + (bc + tx)];
  __syncthreads();
#pragma unroll
  for (int i = 0; i < 32; i += 8)
    out[(size_t)(bc + ty + i) * R + (br + tx)] = f32_to_e4m3(tile[tx][ty + i] * 16.0f);
}

// ---------------- embedding gather ----------------
__global__ void k_gather_e(const int* __restrict__ text,
                           const float* __restrict__ embed,
                           unsigned short* __restrict__ E) {
  int t = blockIdx.x;
  int b = t >> 9, s = t & 511;
  int d = threadIdx.x; // 0..255
#pragma unroll
  for (int j = 0; j < 4; ++j) {
    int sidx = s + j - 4;
    int tok = (sidx >= 0) ? text[b * SS + sidx] : 0;
    float val = (tok != 0) ? embed[(size_t)tok * EMB + d] : 0.0f;
    E[(size_t)t * KDIM + j * EMB + d] = f32_to_bf16(val);
  }
}

// ---------------- FFN GEMM (128x128 tile, relu+bias; OUTQ=1 -> fp8 x16) ----------------
template<int OUTQ>
__global__ __launch_bounds__(256)
void k_gemm_ffn(const unsigned short* __restrict__ A,
                const unsigned short* __restrict__ Bt,
                const float* __restrict__ bias,
                void* __restrict__ Hout, int N) {
  __shared__ unsigned short As[128 * 32];
  __shared__ unsigned short Bs[128 * 32];
  const int tid  = threadIdx.x;
  const int bn   = blockIdx.x, bm = blockIdx.y;
  const int lane = tid & 63, wid = tid >> 6;
  const int wm = wid >> 1, wn = wid & 1;
  const int g = lane >> 4, c = lane & 15;

  f32x4 acc[4][4];
#pragma unroll
  for (int m = 0; m < 4; ++m)
#pragma unroll
    for (int n = 0; n < 4; ++n) { f32x4 z = {0.f, 0.f, 0.f, 0.f}; acc[m][n] = z; }

  const int arow = tid >> 2;
  const int slotb = ((tid & 3) ^ ((tid >> 3) & 3)) * 16;
  const char* gA0 = (const char*)A + ((size_t)(bm * 128 + arow) * KDIM) * 2 + slotb;
  const char* gA1 = gA0 + (size_t)64 * KDIM * 2;
  const char* gB0 = (const char*)Bt + ((size_t)(bn * 128 + arow) * KDIM) * 2 + slotb;
  const char* gB1 = gB0 + (size_t)64 * KDIM * 2;
  char* lA = (char*)As + tid * 16;
  char* lB = (char*)Bs + tid * 16;

  const int rs = (g ^ ((c >> 1) & 3)) * 8;

  for (int kt = 0; kt < KDIM / 32; ++kt) {
    const int kb = kt * 64;
    gload_lds16(gA0 + kb, lA);
    gload_lds16(gA1 + kb, lA + 4096);
    gload_lds16(gB0 + kb, lB);
    gload_lds16(gB1 + kb, lB + 4096);
    __syncthreads();

    bf16x8 af[4], bf[4];
#pragma unroll
    for (int m = 0; m < 4; ++m)
      af[m] = *(const bf16x8*)&As[(wm * 64 + m * 16 + c) * 32 + rs];
#pragma unroll
    for (int n = 0; n < 4; ++n)
      bf[n] = *(const bf16x8*)&Bs[(wn * 64 + n * 16 + c) * 32 + rs];
#pragma unroll
    for (int m = 0; m < 4; ++m)
#pragma unroll
      for (int n = 0; n < 4; ++n)
        acc[m][n] = __builtin_amdgcn_mfma_f32_16x16x32_bf16(af[m], bf[n], acc[m][n], 0, 0, 0);
    __syncthreads();
  }

#pragma unroll
  for (int n = 0; n < 4; ++n) {
    int colg = bn * 128 + wn * 64 + n * 16 + c;
    float bv = bias[colg];
#pragma unroll
    for (int m = 0; m < 4; ++m)
#pragma unroll
      for (int j = 0; j < 4; ++j) {
        int rowg = bm * 128 + wm * 64 + m * 16 + g * 4 + j;
        float v = acc[m][n][j] + bv;
        v = v > 0.f ? v : 0.f;
        if constexpr (OUTQ == 0)
          ((unsigned short*)Hout)[(size_t)rowg * N + colg] = f32_to_bf16(v);
        else
          ((uint8_t*)Hout)[(size_t)rowg * N + colg] = f32_to_e4m3(v * 16.0f);
      }
  }
}

// ---------------- vocab GEMM: MX-fp8, 128x256 block, BK=64, 4 waves ----------------
// A/B pre-scaled by 2^4; MFMA scale operands 2^-4 (e8m0 byte 123).
// R10 = R8's geometry (per-wave 64x128, 1.5 LDS reads/MFMA) x R7's register
// discipline (rolled 2-body loop; full unroll proved to spill in R8/R9).
// acc[2][4]=128 AGPR + ~80 arch ~= 200 unified < 256 cap at (256,2).
__global__ __launch_bounds__(256, 2)
void k_gemm_vocab_mx(const uint8_t* __restrict__ Aq,   // [MTOK][KDIM] fp8 (x16)
                     const uint8_t* __restrict__ Bq,   // [VOCAB][KDIM] fp8 (x16)
                     const float* __restrict__ bias,
                     float* __restrict__ pmax, float* __restrict__ psum,
                     float* __restrict__ tlog, const int* __restrict__ target) {
  __shared__ uint8_t As[2][128 * 64];  // 16 KB
  __shared__ uint8_t Bs[2][256 * 64];  // 32 KB
  const int tid  = threadIdx.x;
  const int lane = tid & 63, wid = tid >> 6;   // 4 waves
  const int wm = wid >> 1, wn = wid & 1;       // 2(M) x 2(N); per-wave out 64x128
  const int lr = lane & 31, kb = lane >> 5;
  const int kb2 = kb << 1;

  // bijective XCD-chunked swizzle; grid = 8000 = 64(bm) x 125(bn)
  const int o   = blockIdx.x;
  const int xcd = o & 7, idx = o >> 3;         // idx 0..999
  const int bm  = xcd * 8 + (idx & 7);         // 0..63
  const int bn  = idx >> 3;                    // 0..124

  f32x16 acc[2][4];
#pragma unroll
  for (int m = 0; m < 2; ++m)
#pragma unroll
    for (int n = 0; n < 4; ++n)
#pragma unroll
      for (int e = 0; e < 16; ++e) acc[m][n][e] = 0.f;

  // staging: thread t -> row (t>>2)+64h, LDS quad t&3; source quad (t&3)^((row>>1)&3)
  const int srow = tid >> 2, sq = tid & 3;
  const int gq = sq ^ ((srow >> 1) & 3);
  const uint8_t* pA = Aq + (size_t)bm * 128 * KDIM + (size_t)srow * KDIM + gq * 16;
  const uint8_t* pB = Bq + (size_t)bn * 256 * KDIM + (size_t)srow * KDIM + gq * 16;
  uint8_t* const lA0 = &As[0][0] + tid * 16;
  uint8_t* const lA1 = &As[1][0] + tid * 16;
  uint8_t* const lB0 = &Bs[0][0] + tid * 16;
  uint8_t* const lB1 = &Bs[1][0] + tid * 16;

  // A: 128 rows = 2 issues (64*KDIM = 65536 B apart); B: 256 rows = 4 issues.
#define STAGE(kt_, d_) do {                                                \
    const size_t ko_ = (size_t)(kt_) * 64;                                 \
    uint8_t* la_ = (d_) ? lA1 : lA0;                                       \
    uint8_t* lb_ = (d_) ? lB1 : lB0;                                       \
    gload_lds16(pA + ko_,          la_);                                   \
    gload_lds16(pA + ko_ + 65536,  la_ + 4096);                            \
    gload_lds16(pB + ko_,          lb_);                                   \
    gload_lds16(pB + ko_ + 65536,  lb_ + 4096);                            \
    gload_lds16(pB + ko_ + 131072, lb_ + 8192);                            \
    gload_lds16(pB + ko_ + 196608, lb_ + 12288);                           \
  } while (0)

  // hoisted read addressing: row bases (buf0) + swizzled quad byte offsets
  const int swz = (lr >> 1) & 3;
  const int q0 = ((kb2 | 0) ^ swz) * 16;
  const int q1 = ((kb2 | 1) ^ swz) * 16;
  const uint8_t* const aR0 = &As[0][(wm * 64 +      lr) * 64];
  const uint8_t* const aR1 = &As[0][(wm * 64 + 32 + lr) * 64];
  const uint8_t* const bR0 = &Bs[0][(wn * 128 +      lr) * 64];
  const uint8_t* const bR1 = &Bs[0][(wn * 128 + 32 + lr) * 64];
  const uint8_t* const bR2 = &Bs[0][(wn * 128 + 64 + lr) * 64];
  const uint8_t* const bR3 = &Bs[0][(wn * 128 + 96 + lr) * 64];

#define RD(dst_, base_, bofs_) do {                                        \
    i32x4 lo_ = *(const i32x4*)((base_) + (bofs_) + q0);                   \
    i32x4 hi_ = *(const i32x4*)((base_) + (bofs_) + q1);                   \
    dst_ = __builtin_shufflevector(lo_, hi_, 0, 1, 2, 3, 4, 5, 6, 7);      \
  } while (0)

  // BODY: consume buffer B_ (K-tile T_); optionally prefetch tile T_+1 into B_^1.
  // As buffer stride 8192 B; Bs buffer stride 16384 B. B_ is a compile-time literal.
#define BODY(B_, T_, DOSTAGE_) do {                                        \
    if (DOSTAGE_) STAGE((T_) + 1, (B_) ^ 1);                               \
    i32x8 b0, b1, b2, b3;                                                  \
    RD(b0, bR0, (B_) * 16384);                                             \
    RD(b1, bR1, (B_) * 16384);                                             \
    RD(b2, bR2, (B_) * 16384);                                             \
    RD(b3, bR3, (B_) * 16384);                                             \
    _Pragma("unroll") for (int m = 0; m < 2; ++m) {                        \
      i32x8 am;                                                            \
      RD(am, (m ? aR1 : aR0), (B_) * 8192);                                \
      __builtin_amdgcn_s_setprio(1);                                       \
      acc[m][0] = __builtin_amdgcn_mfma_scale_f32_32x32x64_f8f6f4(         \
          am, b0, acc[m][0], 0, 0, 0, 123, 0, 123);                        \
      acc[m][1] = __builtin_amdgcn_mfma_scale_f32_32x32x64_f8f6f4(         \
          am, b1, acc[m][1], 0, 0, 0, 123, 0, 123);                        \
      acc[m][2] = __builtin_amdgcn_mfma_scale_f32_32x32x64_f8f6f4(         \
          am, b2, acc[m][2], 0, 0, 0, 123, 0, 123);                        \
      acc[m][3] = __builtin_amdgcn_mfma_scale_f32_32x32x64_f8f6f4(         \
          am, b3, acc[m][3], 0, 0, 0, 123, 0, 123);                        \
      __builtin_amdgcn_s_setprio(0);                                       \
    }                                                                      \
    __syncthreads();                                                       \
  } while (0)

  STAGE(0, 0);
  __syncthreads();  // tile 0 resident

#pragma unroll 1
  for (int ktp = 0; ktp < 8; ++ktp) {
    BODY(0, 2 * ktp,     true);        // stages 2*ktp+1 -> buf1
    BODY(1, 2 * ktp + 1, (ktp < 7));   // stages 2*ktp+2 -> buf0
  }
#undef STAGE
#undef RD
#undef BODY

  // ---- epilogue: fused softmax stats per 64-col chunk (2 chunks/wave) ----
  // C/D 32x32 layout: col = lane&31, row = (reg&3) + 8*(reg>>2) + 4*(lane>>5)
  const int colbase = bn * 256 + wn * 128;
  const int chunk0 = bn * 4 + wn * 2;
  float bov[4];
#pragma unroll
  for (int n = 0; n < 4; ++n) bov[n] = bias[colbase + n * 32 + lr];
#pragma unroll
  for (int m = 0; m < 2; ++m) {
#pragma unroll
    for (int reg = 0; reg < 16; ++reg) {
      int rowg = bm * 128 + wm * 64 + m * 32 + (reg & 3) + 8 * (reg >> 2) + 4 * kb;
      float v0 = acc[m][0][reg] + bov[0];
      float v1 = acc[m][1][reg] + bov[1];
      float v2 = acc[m][2][reg] + bov[2];
      float v3 = acc[m][3][reg] + bov[3];
#pragma unroll
      for (int h = 0; h < 2; ++h) {
        float x0 = (h == 0) ? v0 : v2;
        float x1 = (h == 0) ? v1 : v3;
        float mv = fmaxf(x0, x1);
#pragma unroll
        for (int sft = 1; sft < 32; sft <<= 1) mv = fmaxf(mv, __shfl_xor(mv, sft));
        float se = __expf(x0 - mv) + __expf(x1 - mv);
#pragma unroll
        for (int sft = 1; sft < 32; sft <<= 1) se += __shfl_xor(se, sft);
        if (lr == 0) {
          pmax[(size_t)rowg * PSTRIDE + chunk0 + h] = mv;
          psum[(size_t)rowg * PSTRIDE + chunk0 + h] = se;
        }
      }
      int cwz = target[rowg] - colbase;
      if (cwz >= 0 && cwz < 128 && lr == (cwz & 31)) {
        int nn = cwz >> 5;
        float tv = (nn == 0) ? v0 : (nn == 1) ? v1 : (nn == 2) ? v2 : v3;
        tlog[rowg] = tv;
      }
    }
  }
}

// ---------------- combine per-chunk stats -> nll per row ----------------
__global__ void k_reduce_nll(const float* __restrict__ pmax,
                             const float* __restrict__ psum,
                             const float* __restrict__ tlog,
                             float* __restrict__ nll) {
  int row = blockIdx.x;
  int lane = threadIdx.x; // 64
  float M = -1e30f;
  for (int ch = lane; ch < NCHUNK; ch += 64) M = fmaxf(M, pmax[(size_t)row * PSTRIDE + ch]);
#pragma unroll
  for (int s = 1; s < 64; s <<= 1) M = fmaxf(M, __shfl_xor(M, s));
  float L = 0.f;
  for (int ch = lane; ch < NCHUNK; ch += 64)
    L += __expf(pmax[(size_t)row * PSTRIDE + ch] - M) * psum[(size_t)row * PSTRIDE + ch];
#pragma unroll
  for (int s = 1; s < 64; s <<= 1) L += __shfl_xor(L, s);
  if (lane == 0) nll[row] = -(tlog[row] - M - logf(L));
}

// ---------------- masked per-step mean -> scalar loss ----------------
__global__ void k_loss(const int* __restrict__ target,
                       const float* __restrict__ nll,
                       float* __restrict__ out) {
  __shared__ float red[SS];
  int s = threadIdx.x; // 512
  float sl = 0.f, cnt = 0.f;
#pragma unroll
  for (int b = 0; b < NB; ++b) {
    int idx = b * SS + s;
    if (target[idx] != 0) { sl += nll[idx]; cnt += 1.f; }
  }
  red[s] = sl / fmaxf(cnt, 1.f);
  __syncthreads();
  for (int st = 256; st > 0; st >>= 1) {
    if (s < st) red[s] += red[s + st];
    __syncthreads();
  }
  if (s == 0) out[0] = red[0] / (float)SS;
}

// ---------------- launch ----------------
extern "C" void kernel_launch(void* const* d_in, const int* in_sizes, int n_in,
                              void* d_out, int out_size, void* d_ws, size_t ws_size,
                              hipStream_t stream) {
  (void)in_sizes; (void)n_in; (void)out_size; (void)ws_size;
  const int*   text   = (const int*)d_in[0];
  const int*   target = (const int*)d_in[1];
  const float* embed  = (const float*)d_in[2];
  const float* W1     = (const float*)d_in[3];
  const float* b1     = (const float*)d_in[4];
  const float* W2     = (const float*)d_in[5];
  const float* b2     = (const float*)d_in[6];
  const float* Wo     = (const float*)d_in[7];
  const float* bo     = (const float*)d_in[8];
  float* out = (float*)d_out;
  char* ws = (char*)d_ws;

  const size_t SZ_E = (size_t)MTOK * KDIM * 2;          // 16.78 MB (bf16)
  unsigned short* E   = (unsigned short*)(ws);
  unsigned short* H1  = (unsigned short*)(ws + SZ_E);
  uint8_t*        H2Q = (uint8_t*)(ws + 2 * SZ_E);      // fp8, 8.39 MB
  char* p = ws + 2 * SZ_E + (size_t)MTOK * KDIM;
  unsigned short* W1t = (unsigned short*)p;  p += (size_t)HID * HID * 2;
  unsigned short* W2t = (unsigned short*)p;  p += (size_t)HID * HID * 2;
  uint8_t*        WoQ = (uint8_t*)p;         p += (size_t)VOCAB * HID;   // fp8, 32.77 MB
  float* tlog = (float*)p;                   p += (size_t)MTOK * 4;
  float* nll  = (float*)p;
  float* pmax = (float*)E;   // E dead after GEMM1
  float* psum = (float*)H1;  // H1 dead after GEMM2

  k_transpose_bf16<<<dim3(HID / 32, HID / 32), 256, 0, stream>>>(W1, W1t, HID, HID);
  k_transpose_bf16<<<dim3(HID / 32, HID / 32), 256, 0, stream>>>(W2, W2t, HID, HID);
  k_transpose_fp8 <<<dim3(VOCAB / 32, HID / 32), 256, 0, stream>>>(Wo, WoQ, HID, VOCAB);
  k_gather_e<<<MTOK, 256, 0, stream>>>(text, embed, E);

  k_gemm_ffn<0><<<dim3(HID / 128, MTOK / 128), 256, 0, stream>>>(E, W1t, b1, (void*)H1, HID);
  k_gemm_ffn<1><<<dim3(HID / 128, MTOK / 128), 256, 0, stream>>>(H1, W2t, b2, (void*)H2Q, HID);

  k_gemm_vocab_mx<<<dim3((MTOK / 128) * (VOCAB / 256)), 256, 0, stream>>>(
      H2Q, WoQ, bo, pmax, psum, tlog, target);

  k_reduce_nll<<<MTOK, 64, 0, stream>>>(pmax, psum, tlog, nll);
  k_loss<<<1, SS, 0, stream>>>(target, nll, out);
}

// Round 11
// 636.408 us; speedup vs baseline: 3.5939x; 1.2326x over previous
//
#include <hip/hip_runtime.h>
#include <cstdint>
#include <cstddef>

// ---------------- problem constants ----------------
#define VOCAB 32000
#define EMB   256
#define HID   1024
#define NB    16      // batch
#define SS    512     // seq
#define MTOK  (NB*SS) // 8192 tokens
#define KDIM  1024    // NM1*EMB = HID
#define NCHUNK 500    // 32000 / 64 cols per chunk
#define PSTRIDE 512   // padded chunk stride

typedef __bf16 bf16_t;
typedef bf16_t bf16x8 __attribute__((ext_vector_type(8)));
typedef float  f32x4  __attribute__((ext_vector_type(4)));
typedef float  f32x16 __attribute__((ext_vector_type(16)));
typedef int    i32x4  __attribute__((ext_vector_type(4)));
typedef int    i32x8  __attribute__((ext_vector_type(8)));

__device__ __forceinline__ unsigned short f32_to_bf16(float f) {
  union { float f; unsigned int u; } v; v.f = f;
  unsigned int u = v.u;
  unsigned int r = (u + 0x7FFFu + ((u >> 16) & 1u)) >> 16; // RNE
  return (unsigned short)r;
}

// f32 -> OCP e4m3fn, RNE, software (input assumed |x| <= 448)
__device__ __forceinline__ uint8_t f32_to_e4m3(float x) {
  union { float f; uint32_t u; } v; v.f = x;
  uint32_t s = (v.u >> 24) & 0x80u;
  int e = (int)((v.u >> 23) & 0xffu) - 127;
  uint32_t m = v.u & 0x7fffffu;
  if (e < -9) return (uint8_t)s;                  // -> 0
  if (e >= -6) {                                  // normal range
    uint32_t keep = m >> 20;
    uint32_t rest = m & 0xfffffu;
    keep += (rest > 0x80000u) || (rest == 0x80000u && (keep & 1u));
    if (keep == 8u) { keep = 0u; e += 1; }
    int code = ((e + 7) << 3) | (int)keep;
    if (code >= 0x7f) code = 0x7e;                // clamp to 448 (avoid NaN)
    return (uint8_t)(s | (uint32_t)code);
  }
  // subnormal
  uint32_t full = 0x800000u | m;
  int shift = 20 + (-6 - e);                      // 21..23
  uint32_t keep = full >> shift;
  uint32_t rest = full & ((1u << shift) - 1u);
  uint32_t half = 1u << (shift - 1);
  keep += (rest > half) || (rest == half && (keep & 1u));
  if (keep >= 8u) return (uint8_t)(s | 0x08u);
  return (uint8_t)(s | keep);
}

__device__ __forceinline__ void gload_lds16(const void* gsrc, void* ldst) {
  __builtin_amdgcn_global_load_lds(
      (__attribute__((address_space(1))) void*)gsrc,
      (__attribute__((address_space(3))) void*)ldst,
      16, 0, 0);
}

// ---------------- transpose + convert: in[R][C] f32 -> out[C][R] ----------------
__global__ void k_transpose_bf16(const float* __restrict__ in,
                                 unsigned short* __restrict__ out,
                                 int R, int C) {
  __shared__ float tile[32][33];
  int bc = blockIdx.x * 32, br = blockIdx.y * 32;
  int tx = threadIdx.x & 31, ty = threadIdx.x >> 5;
#pragma unroll
  for (int i = 0; i < 32; i += 8)
    tile[ty + i][tx] = in[(size_t)(br + ty + i) * C + (bc + tx)];
  __syncthreads();
#pragma unroll
  for (int i = 0; i < 32; i += 8)
    out[(size_t)(bc + ty + i) * R + (br + tx)] = f32_to_bf16(tile[tx][ty + i]);
}

__global__ void k_transpose_fp8(const float* __restrict__ in,
                                uint8_t* __restrict__ out,
                                int R, int C) {
  __shared__ float tile[32][33];
  int bc = blockIdx.x * 32, br = blockIdx.y * 32;
  int tx = threadIdx.x & 31, ty = threadIdx.x >> 5;
#pragma unroll
  for (int i = 0; i < 32; i += 8)
    tile[ty + i][tx] = in[(size_t)(br + ty + i) * C + (bc + tx)];
  __syncthreads();
#pragma unroll
  for (int i = 0; i < 32; i += 8)
    out[(size_t)(bc + ty + i) * R + (br + tx)] = f32_to_e4m3(tile[tx][ty + i] * 16.0f);
}

// ---------------- embedding gather ----------------
__global__ void k_gather_e(const int* __restrict__ text,
                           const float* __restrict__ embed,
                           unsigned short* __restrict__ E) {
  int t = blockIdx.x;
  int b = t >> 9, s = t & 511;
  int d = threadIdx.x; // 0..255
#pragma unroll
  for (int j = 0; j < 4; ++j) {
    int sidx = s + j - 4;
    int tok = (sidx >= 0) ? text[b * SS + sidx] : 0;
    float val = (tok != 0) ? embed[(size_t)tok * EMB + d] : 0.0f;
    E[(size_t)t * KDIM + j * EMB + d] = f32_to_bf16(val);
  }
}

// ---------------- FFN GEMM (128x128 tile, relu+bias; OUTQ=1 -> fp8 x16) ----------------
template<int OUTQ>
__global__ __launch_bounds__(256)
void k_gemm_ffn(const unsigned short* __restrict__ A,
                const unsigned short* __restrict__ Bt,
                const float* __restrict__ bias,
                void* __restrict__ Hout, int N) {
  __shared__ unsigned short As[128 * 32];
  __shared__ unsigned short Bs[128 * 32];
  const int tid  = threadIdx.x;
  const int bn   = blockIdx.x, bm = blockIdx.y;
  const int lane = tid & 63, wid = tid >> 6;
  const int wm = wid >> 1, wn = wid & 1;
  const int g = lane >> 4, c = lane & 15;

  f32x4 acc[4][4];
#pragma unroll
  for (int m = 0; m < 4; ++m)
#pragma unroll
    for (int n = 0; n < 4; ++n) { f32x4 z = {0.f, 0.f, 0.f, 0.f}; acc[m][n] = z; }

  const int arow = tid >> 2;
  const int slotb = ((tid & 3) ^ ((tid >> 3) & 3)) * 16;
  const char* gA0 = (const char*)A + ((size_t)(bm * 128 + arow) * KDIM) * 2 + slotb;
  const char* gA1 = gA0 + (size_t)64 * KDIM * 2;
  const char* gB0 = (const char*)Bt + ((size_t)(bn * 128 + arow) * KDIM) * 2 + slotb;
  const char* gB1 = gB0 + (size_t)64 * KDIM * 2;
  char* lA = (char*)As + tid * 16;
  char* lB = (char*)Bs + tid * 16;

  const int rs = (g ^ ((c >> 1) & 3)) * 8;

  for (int kt = 0; kt < KDIM / 32; ++kt) {
    const int kb = kt * 64;
    gload_lds16(gA0 + kb, lA);
    gload_lds16(gA1 + kb, lA + 4096);
    gload_lds16(gB0 + kb, lB);
    gload_lds16(gB1 + kb, lB + 4096);
    __syncthreads();

    bf16x8 af[4], bf[4];
#pragma unroll
    for (int m = 0; m < 4; ++m)
      af[m] = *(const bf16x8*)&As[(wm * 64 + m * 16 + c) * 32 + rs];
#pragma unroll
    for (int n = 0; n < 4; ++n)
      bf[n] = *(const bf16x8*)&Bs[(wn * 64 + n * 16 + c) * 32 + rs];
#pragma unroll
    for (int m = 0; m < 4; ++m)
#pragma unroll
      for (int n = 0; n < 4; ++n)
        acc[m][n] = __builtin_amdgcn_mfma_f32_16x16x32_bf16(af[m], bf[n], acc[m][n], 0, 0, 0);
    __syncthreads();
  }

#pragma unroll
  for (int n = 0; n < 4; ++n) {
    int colg = bn * 128 + wn * 64 + n * 16 + c;
    float bv = bias[colg];
#pragma unroll
    for (int m = 0; m < 4; ++m)
#pragma unroll
      for (int j = 0; j < 4; ++j) {
        int rowg = bm * 128 + wm * 64 + m * 16 + g * 4 + j;
        float v = acc[m][n][j] + bv;
        v = v > 0.f ? v : 0.f;
        if constexpr (OUTQ == 0)
          ((unsigned short*)Hout)[(size_t)rowg * N + colg] = f32_to_bf16(v);
        else
          ((uint8_t*)Hout)[(size_t)rowg * N + colg] = f32_to_e4m3(v * 16.0f);
      }
  }
}

// ---------------- vocab GEMM: MX-fp8, 256x128 block, BK=64, 8 waves ----------------
// A/B pre-scaled by 2^4; MFMA scale operands 2^-4 (e8m0 byte 123).
// R11 = R7's per-wave structure (64x64 out, acc[2][2]=64 AGPR, rolled 2-body loop,
// ~64 arch VGPR -> 128 unified = the 16-waves/CU breakpoint) scaled to 8 waves/block:
// block 256x128 (4M x 2N), 2 blocks/CU target -> 16 waves/CU, staged LDS bytes/MFMA
// 1.0 -> 0.75 KB, 3 gloads/thread/tile (was 4). Occupancy is the proven lever
// (R7 occ45% 572us > R10 occ23% 716us at better read-ratio).
__global__ __launch_bounds__(512, 2)
void k_gemm_vocab_mx(const uint8_t* __restrict__ Aq,   // [MTOK][KDIM] fp8 (x16)
                     const uint8_t* __restrict__ Bq,   // [VOCAB][KDIM] fp8 (x16)
                     const float* __restrict__ bias,
                     float* __restrict__ pmax, float* __restrict__ psum,
                     float* __restrict__ tlog, const int* __restrict__ target) {
  __shared__ uint8_t As[2][256 * 64];  // 32 KB
  __shared__ uint8_t Bs[2][128 * 64];  // 16 KB
  const int tid  = threadIdx.x;
  const int lane = tid & 63, wid = tid >> 6;   // 8 waves
  const int wm = wid >> 1, wn = wid & 1;       // 4(M) x 2(N); per-wave out 64x64
  const int lr = lane & 31, kb = lane >> 5;
  const int kb2 = kb << 1;

  // bijective XCD-chunked swizzle; grid = 8000 = 32(bm) x 250(bn)
  const int o   = blockIdx.x;
  const int xcd = o & 7, idx = o >> 3;         // idx 0..999
  const int bm  = xcd * 4 + (idx & 3);         // 0..31
  const int bn  = idx >> 2;                    // 0..249

  f32x16 acc[2][2];
#pragma unroll
  for (int m = 0; m < 2; ++m)
#pragma unroll
    for (int n = 0; n < 2; ++n)
#pragma unroll
      for (int e = 0; e < 16; ++e) acc[m][n][e] = 0.f;

  // staging: thread t -> row (t>>2) (+128 for A's 2nd issue), LDS quad t&3;
  // source quad (t&3)^((row>>1)&3); invariant under row += 128.
  const int srow = tid >> 2, sq = tid & 3;     // srow 0..127 (512 threads)
  const int gq = sq ^ ((srow >> 1) & 3);
  const uint8_t* pA = Aq + (size_t)bm * 256 * KDIM + (size_t)srow * KDIM + gq * 16;
  const uint8_t* pB = Bq + (size_t)bn * 128 * KDIM + (size_t)srow * KDIM + gq * 16;
  uint8_t* const lA0 = &As[0][0] + tid * 16;   // 512*16 = 8 KB = 128 rows
  uint8_t* const lA1 = &As[1][0] + tid * 16;
  uint8_t* const lB0 = &Bs[0][0] + tid * 16;
  uint8_t* const lB1 = &Bs[1][0] + tid * 16;

  // A: 256 rows = 2 issues (128*KDIM = 131072 B apart); B: 128 rows = 1 issue.
#define STAGE(kt_, d_) do {                                                \
    const size_t ko_ = (size_t)(kt_) * 64;                                 \
    uint8_t* la_ = (d_) ? lA1 : lA0;                                       \
    uint8_t* lb_ = (d_) ? lB1 : lB0;                                       \
    gload_lds16(pA + ko_,          la_);                                   \
    gload_lds16(pA + ko_ + 131072, la_ + 8192);                            \
    gload_lds16(pB + ko_,          lb_);                                   \
  } while (0)

  // hoisted read addressing: row bases (buf0) + swizzled quad byte offsets
  // row = wm*64 (+32) + lr: (row>>1)&3 == (lr>>1)&3 since wm*32, 16 are mult of 4.
  const int swz = (lr >> 1) & 3;
  const int q0 = ((kb2 | 0) ^ swz) * 16;
  const int q1 = ((kb2 | 1) ^ swz) * 16;
  const uint8_t* const aR0 = &As[0][(wm * 64 +      lr) * 64];
  const uint8_t* const aR1 = &As[0][(wm * 64 + 32 + lr) * 64];
  const uint8_t* const bR0 = &Bs[0][(wn * 64 +      lr) * 64];
  const uint8_t* const bR1 = &Bs[0][(wn * 64 + 32 + lr) * 64];

#define RD(dst_, base_, bofs_) do {                                        \
    i32x4 lo_ = *(const i32x4*)((base_) + (bofs_) + q0);                   \
    i32x4 hi_ = *(const i32x4*)((base_) + (bofs_) + q1);                   \
    dst_ = __builtin_shufflevector(lo_, hi_, 0, 1, 2, 3, 4, 5, 6, 7);      \
  } while (0)

  // BODY: consume buffer B_ (K-tile T_); optionally prefetch tile T_+1 into B_^1.
  // As buffer stride 16384 B; Bs buffer stride 8192 B. B_ is a compile-time literal.
#define BODY(B_, T_, DOSTAGE_) do {                                        \
    if (DOSTAGE_) STAGE((T_) + 1, (B_) ^ 1);                               \
    i32x8 b0, b1, a0, a1;                                                  \
    RD(b0, bR0, (B_) * 8192);                                              \
    RD(b1, bR1, (B_) * 8192);                                              \
    RD(a0, aR0, (B_) * 16384);                                             \
    RD(a1, aR1, (B_) * 16384);                                             \
    __builtin_amdgcn_s_setprio(1);                                         \
    acc[0][0] = __builtin_amdgcn_mfma_scale_f32_32x32x64_f8f6f4(           \
        a0, b0, acc[0][0], 0, 0, 0, 123, 0, 123);                          \
    acc[0][1] = __builtin_amdgcn_mfma_scale_f32_32x32x64_f8f6f4(           \
        a0, b1, acc[0][1], 0, 0, 0, 123, 0, 123);                          \
    acc[1][0] = __builtin_amdgcn_mfma_scale_f32_32x32x64_f8f6f4(           \
        a1, b0, acc[1][0], 0, 0, 0, 123, 0, 123);                          \
    acc[1][1] = __builtin_amdgcn_mfma_scale_f32_32x32x64_f8f6f4(           \
        a1, b1, acc[1][1], 0, 0, 0, 123, 0, 123);                          \
    __builtin_amdgcn_s_setprio(0);                                         \
    __syncthreads();                                                       \
  } while (0)

  STAGE(0, 0);
  __syncthreads();  // tile 0 resident

#pragma unroll 1
  for (int ktp = 0; ktp < 8; ++ktp) {
    BODY(0, 2 * ktp,     true);        // stages 2*ktp+1 -> buf1
    BODY(1, 2 * ktp + 1, (ktp < 7));   // stages 2*ktp+2 -> buf0
  }
#undef STAGE
#undef RD
#undef BODY

  // ---- epilogue: fused softmax stats per 64-col wave chunk ----
  // C/D 32x32 layout: col = lane&31, row = (reg&3) + 8*(reg>>2) + 4*(lane>>5)
  const int chunk = bn * 2 + wn;
  const int colbase = bn * 128 + wn * 64;
  float bov0 = bias[colbase + lr];
  float bov1 = bias[colbase + 32 + lr];
#pragma unroll
  for (int m = 0; m < 2; ++m) {
#pragma unroll
    for (int reg = 0; reg < 16; ++reg) {
      int rowg = bm * 256 + wm * 64 + m * 32 + (reg & 3) + 8 * (reg >> 2) + 4 * kb;
      float v0 = acc[m][0][reg] + bov0;
      float v1 = acc[m][1][reg] + bov1;
      float mv = fmaxf(v0, v1);
#pragma unroll
      for (int sft = 1; sft < 32; sft <<= 1) mv = fmaxf(mv, __shfl_xor(mv, sft));
      float se = __expf(v0 - mv) + __expf(v1 - mv);
#pragma unroll
      for (int sft = 1; sft < 32; sft <<= 1) se += __shfl_xor(se, sft);
      if (lr == 0) {
        pmax[(size_t)rowg * PSTRIDE + chunk] = mv;
        psum[(size_t)rowg * PSTRIDE + chunk] = se;
      }
      int cw = target[rowg] - colbase;
      if (cw >= 0 && cw < 64 && lr == (cw & 31)) {
        tlog[rowg] = (cw < 32) ? v0 : v1;
      }
    }
  }
}

// ---------------- combine per-chunk stats -> nll per row ----------------
__global__ void k_reduce_nll(const float* __restrict__ pmax,
                             const float* __restrict__ psum,
                             const float* __restrict__ tlog,
                             float* __restrict__ nll) {
  int row = blockIdx.x;
  int lane = threadIdx.x; // 64
  float M = -1e30f;
  for (int ch = lane; ch < NCHUNK; ch += 64) M = fmaxf(M, pmax[(size_t)row * PSTRIDE + ch]);
#pragma unroll
  for (int s = 1; s < 64; s <<= 1) M = fmaxf(M, __shfl_xor(M, s));
  float L = 0.f;
  for (int ch = lane; ch < NCHUNK; ch += 64)
    L += __expf(pmax[(size_t)row * PSTRIDE + ch] - M) * psum[(size_t)row * PSTRIDE + ch];
#pragma unroll
  for (int s = 1; s < 64; s <<= 1) L += __shfl_xor(L, s);
  if (lane == 0) nll[row] = -(tlog[row] - M - logf(L));
}

// ---------------- masked per-step mean -> scalar loss ----------------
__global__ void k_loss(const int* __restrict__ target,
                       const float* __restrict__ nll,
                       float* __restrict__ out) {
  __shared__ float red[SS];
  int s = threadIdx.x; // 512
  float sl = 0.f, cnt = 0.f;
#pragma unroll
  for (int b = 0; b < NB; ++b) {
    int idx = b * SS + s;
    if (target[idx] != 0) { sl += nll[idx]; cnt += 1.f; }
  }
  red[s] = sl / fmaxf(cnt, 1.f);
  __syncthreads();
  for (int st = 256; st > 0; st >>= 1) {
    if (s < st) red[s] += red[s + st];
    __syncthreads();
  }
  if (s == 0) out[0] = red[0] / (float)SS;
}

// ---------------- launch ----------------
extern "C" void kernel_launch(void* const* d_in, const int* in_sizes, int n_in,
                              void* d_out, int out_size, void* d_ws, size_t ws_size,
                              hipStream_t stream) {
  (void)in_sizes; (void)n_in; (void)out_size; (void)ws_size;
  const int*   text   = (const int*)d_in[0];
  const int*   target = (const int*)d_in[1];
  const float* embed  = (const float*)d_in[2];
  const float* W1     = (const float*)d_in[3];
  const float* b1     = (const float*)d_in[4];
  const float* W2     = (const float*)d_in[5];
  const float* b2     = (const float*)d_in[6];
  const float* Wo     = (const float*)d_in[7];
  const float* bo     = (const float*)d_in[8];
  float* out = (float*)d_out;
  char* ws = (char*)d_ws;

  const size_t SZ_E = (size_t)MTOK * KDIM * 2;          // 16.78 MB (bf16)
  unsigned short* E   = (unsigned short*)(ws);
  unsigned short* H1  = (unsigned short*)(ws + SZ_E);
  uint8_t*        H2Q = (uint8_t*)(ws + 2 * SZ_E);      // fp8, 8.39 MB
  char* p = ws + 2 * SZ_E + (size_t)MTOK * KDIM;
  unsigned short* W1t = (unsigned short*)p;  p += (size_t)HID * HID * 2;
  unsigned short* W2t = (unsigned short*)p;  p += (size_t)HID * HID * 2;
  uint8_t*        WoQ = (uint8_t*)p;         p += (size_t)VOCAB * HID;   // fp8, 32.77 MB
  float* tlog = (float*)p;                   p += (size_t)MTOK * 4;
  float* nll  = (float*)p;
  float* pmax = (float*)E;   // E dead after GEMM1
  float* psum = (float*)H1;  // H1 dead after GEMM2

  k_transpose_bf16<<<dim3(HID / 32, HID / 32), 256, 0, stream>>>(W1, W1t, HID, HID);
  k_transpose_bf16<<<dim3(HID / 32, HID / 32), 256, 0, stream>>>(W2, W2t, HID, HID);
  k_transpose_fp8 <<<dim3(VOCAB / 32, HID / 32), 256, 0, stream>>>(Wo, WoQ, HID, VOCAB);
  k_gather_e<<<MTOK, 256, 0, stream>>>(text, embed, E);

  k_gemm_ffn<0><<<dim3(HID / 128, MTOK / 128), 256, 0, stream>>>(E, W1t, b1, (void*)H1, HID);
  k_gemm_ffn<1><<<dim3(HID / 128, MTOK / 128), 256, 0, stream>>>(H1, W2t, b2, (void*)H2Q, HID);

  k_gemm_vocab_mx<<<dim3((MTOK / 256) * (VOCAB / 128)), 512, 0, stream>>>(
      H2Q, WoQ, bo, pmax, psum, tlog, target);

  k_reduce_nll<<<MTOK, 64, 0, stream>>>(pmax, psum, tlog, nll);
  k_loss<<<1, SS, 0, stream>>>(target, nll, out);
}